// Round 1
// 2205.691 us; speedup vs baseline: 1.0599x; 1.0599x over previous
//
#include <hip/hip_runtime.h>
#include <hip/hip_bf16.h>

// ActivePerceptionLayer: B=8192, IN=512, D=256, F=64, A=128, H=8, HD=16, BUDGET=16
//
// Pipeline:
//  K0 : fuse M = op_w @ out_proj_w [512,128], b' = op_b + op_w @ out_proj_b
//  K0b: convert enc_w + in_proj_w to bf16 (weights re-read by 4096 K2 blocks)
//  G1 : SGEMM H1[8192,256] = relu(X @ [ue_w1;fi_w1]^T + b)   (fp32, bit-exact chain)
//  G2 : epilogue: uncertainty + fi out-proj + softmax -> out_unc/out_fi/FIws
//  G3 : SGEMM H2[8192,128] = relu([X | FI] @ sd_w1^T + b)    (K=576 concat)
//  G4 : sd out-proj + sigmoid + top-16 select + mask/cost + feature grouping
//  K2 : MFMA per feature-group: 32 rows/block (enc GEMM + qkv projection, bf16)
//  K3 : collapsed attention (48 masked positions share qkv=in_proj_b -> 17x17)
//  K4 : enhanced_x = x + mean_ctx @ M^T + b'
//
// G1..G4 replace the old monolithic k1_mlp (880us, VALUBusy 9.7%, 2 blocks/CU,
// ~1 LDS scalar read per FMA). All selection-path arithmetic keeps the exact
// same fp32 FMA accumulation order (k-ascending, single accumulator, bias-add
// then ReLU, same shuffle butterflies) -> outputs bit-identical to prior pass.
//
// Workspace (~107.3 MB): qkv bf16 (low 14.7MB aliased by H1/H2/FI during G1-G4)
//   | enc_w_bf 4MB (aliased by mean_ctx after K2) | ipw_bf | M | b' | rows | counts

#define NB 8192

typedef __attribute__((ext_vector_type(8))) short short8;
typedef __attribute__((ext_vector_type(4))) float f32x4;

// ---------------- K0: fold out_proj and output_projection ----------------
__global__ __launch_bounds__(256) void k0_fuse(
    const float* __restrict__ op_w, const float* __restrict__ out_proj_w,
    const float* __restrict__ out_proj_b, const float* __restrict__ op_b,
    float* __restrict__ M, float* __restrict__ bf)
{
  int g = blockIdx.x;
  if (g < 256) {
    int t = g * 256 + threadIdx.x;       // 0..65535
    int i = t >> 7, j = t & 127;         // M[i][j] = sum_k op_w[i][k]*out_proj_w[k][j]
    float acc = 0.f;
    for (int k = 0; k < 128; k++) acc += op_w[i * 128 + k] * out_proj_w[k * 128 + j];
    M[i * 128 + j] = acc;
  } else {
    for (int ii = threadIdx.x; ii < 512; ii += 256) {
      float acc = op_b[ii];
      for (int k = 0; k < 128; k++) acc += op_w[ii * 128 + k] * out_proj_b[k];
      bf[ii] = acc;
    }
  }
}

// ---------------- K0b: fp32 -> bf16 weight conversion ----------------
__global__ __launch_bounds__(256) void k0b_cvt(
    const float* __restrict__ encw, const float* __restrict__ ipw,
    __hip_bfloat16* __restrict__ encw_bf, __hip_bfloat16* __restrict__ ipw_bf)
{
  const int NE = 64 * 128 * 256;            // 2,097,152 (mult of 4)
  const int NT4 = (NE + 384 * 128) / 4;     // 536,576 groups of 4
  int i4 = blockIdx.x * 256 + threadIdx.x;
  if (i4 >= NT4) return;
  int i = i4 * 4;
  float4 v = (i < NE) ? *(const float4*)(encw + i)
                      : *(const float4*)(ipw + (i - NE));
  union { __hip_bfloat16 h[4]; short4 s; } u;
  u.h[0] = __float2bfloat16(v.x); u.h[1] = __float2bfloat16(v.y);
  u.h[2] = __float2bfloat16(v.z); u.h[3] = __float2bfloat16(v.w);
  if (i < NE) *(short4*)(encw_bf + i) = u.s;
  else        *(short4*)(ipw_bf + (i - NE)) = u.s;
}

// ---------------- shared epilogue helper (verbatim arithmetic) ----------------
__device__ __forceinline__ void mlp_out64(const float* __restrict__ w2,
                                          const float* __restrict__ b2,
                                          const float (*h1)[129], float (*wt2)[33],
                                          float (*fl)[64], int t)
{
  const int o = t & 63, rg4 = t >> 6;
  const int ol = t >> 2, kb = (t & 3) * 8;
  float acc[4];
#pragma unroll
  for (int rr = 0; rr < 4; rr++) acc[rr] = 0.f;
  for (int kc = 0; kc < 128; kc += 32) {
    __syncthreads();
    const float* wr = w2 + ol * 128 + kc + kb;
#pragma unroll
    for (int q = 0; q < 8; q++) wt2[ol][kb + q] = wr[q];
    __syncthreads();
#pragma unroll
    for (int kk = 0; kk < 32; kk++) {
      float w = wt2[o][kk];
#pragma unroll
      for (int rr = 0; rr < 4; rr++)
        acc[rr] += w * h1[rg4 * 4 + rr][kc + kk];
    }
  }
  float bv = b2[o];
#pragma unroll
  for (int rr = 0; rr < 4; rr++) fl[rg4 * 4 + rr][o] = acc[rr] + bv;
}

// ---------------- G1: H1[8192,256] = relu(X @ [ue_w1;fi_w1]^T + b) ----------------
// BM=64, BN=64, BK=32, 256 threads, 4x4 per thread. Grid (128, 4).
// Each output accumulates k=0..511 ascending via fp32 FMA chain (bit-exact
// vs the old mlp_h1), then +bias, relu.
__global__ __launch_bounds__(256) void g1_h1(
    const float* __restrict__ x,
    const float* __restrict__ ue_w1, const float* __restrict__ ue_b1,
    const float* __restrict__ fi_w1, const float* __restrict__ fi_b1,
    float* __restrict__ H1)
{
  __shared__ __align__(16) float Xs[32][68];   // [k][m], 68 pad: 16B-aligned rows
  __shared__ __align__(16) float Ws[32][68];   // [k][n]
  const int t = threadIdx.x;
  const int bm0 = blockIdx.x * 64;
  const int bn0 = blockIdx.y * 64;             // 0,64 -> ue ; 128,192 -> fi
  const float* __restrict__ W    = (bn0 < 128) ? ue_w1 : fi_w1;
  const float* __restrict__ bias = (bn0 < 128) ? ue_b1 : fi_b1;
  const int wr0 = bn0 & 127;
  const int tm = t & 15, tn = t >> 4;
  float acc[4][4];
#pragma unroll
  for (int i = 0; i < 4; i++)
#pragma unroll
    for (int j = 0; j < 4; j++) acc[i][j] = 0.f;

  for (int kc = 0; kc < 512; kc += 32) {
    __syncthreads();
#pragma unroll
    for (int s = 0; s < 2; s++) {
      int jj = t + s * 256;
      int row = jj >> 3, kq = jj & 7;
      float4 v = *(const float4*)(x + (size_t)(bm0 + row) * 512 + kc + kq * 4);
      Xs[kq * 4 + 0][row] = v.x; Xs[kq * 4 + 1][row] = v.y;
      Xs[kq * 4 + 2][row] = v.z; Xs[kq * 4 + 3][row] = v.w;
      float4 w = *(const float4*)(W + (size_t)(wr0 + row) * 512 + kc + kq * 4);
      Ws[kq * 4 + 0][row] = w.x; Ws[kq * 4 + 1][row] = w.y;
      Ws[kq * 4 + 2][row] = w.z; Ws[kq * 4 + 3][row] = w.w;
    }
    __syncthreads();
#pragma unroll
    for (int kk = 0; kk < 32; kk++) {
      float4 xv = *(const float4*)&Xs[kk][tm * 4];
      float4 wv = *(const float4*)&Ws[kk][tn * 4];
      float xa[4] = {xv.x, xv.y, xv.z, xv.w};
      float wa[4] = {wv.x, wv.y, wv.z, wv.w};
#pragma unroll
      for (int i = 0; i < 4; i++)
#pragma unroll
        for (int j = 0; j < 4; j++) acc[i][j] += xa[i] * wa[j];
    }
  }
  const int rm = bm0 + tm * 4;
  const int cn = tn * 4;
  float bv[4];
#pragma unroll
  for (int j = 0; j < 4; j++) bv[j] = bias[wr0 + cn + j];
#pragma unroll
  for (int i = 0; i < 4; i++) {
    float4 o;
    float v0 = acc[i][0] + bv[0]; o.x = v0 > 0.f ? v0 : 0.f;
    float v1 = acc[i][1] + bv[1]; o.y = v1 > 0.f ? v1 : 0.f;
    float v2 = acc[i][2] + bv[2]; o.z = v2 > 0.f ? v2 : 0.f;
    float v3 = acc[i][3] + bv[3]; o.w = v3 > 0.f ? v3 : 0.f;
    *(float4*)(H1 + (size_t)(rm + i) * 256 + bn0 + cn) = o;
  }
}

// ---------------- G2: uncertainty + fi out-proj + softmax ----------------
// 16 rows/block, 512 blocks. Arithmetic verbatim from old k1.
__global__ __launch_bounds__(256) void g2_fi(
    const float* __restrict__ H1,
    const float* __restrict__ ue_w2, const float* __restrict__ ue_b2,
    const float* __restrict__ fi_w2, const float* __restrict__ fi_b2,
    float* __restrict__ out_unc, float* __restrict__ out_fi,
    float* __restrict__ fi_ws)
{
  __shared__ float hue[16][129];
  __shared__ float hfi[16][129];
  __shared__ float wt_raw[64 * 33 + 16 * 64];
  float (*wt)[33] = (float(*)[33])wt_raw;
  float (*fl)[64] = (float(*)[64])(wt_raw + 64 * 33);
  const int t = threadIdx.x;
  const int b0 = blockIdx.x * 16;
  // stage H1 rows: cols 0..127 -> hue, 128..255 -> hfi
#pragma unroll
  for (int s = 0; s < 4; s++) {
    int jj = t + s * 256;
    int row = jj >> 6, f4 = jj & 63;
    float4 v = *(const float4*)(H1 + (size_t)(b0 + row) * 256 + f4 * 4);
    if (f4 < 32) {
      int c = f4 * 4;
      hue[row][c] = v.x; hue[row][c + 1] = v.y; hue[row][c + 2] = v.z; hue[row][c + 3] = v.w;
    } else {
      int c = (f4 - 32) * 4;
      hfi[row][c] = v.x; hfi[row][c + 1] = v.y; hfi[row][c + 2] = v.z; hfi[row][c + 3] = v.w;
    }
  }
  __syncthreads();
  if (t < 16) {
    float a = ue_b2[0];
    for (int k = 0; k < 128; k++) a += ue_w2[k] * hue[t][k];
    float u = 1.f / (1.f + expf(-a));
    out_unc[b0 + t] = u;
  }
  mlp_out64(fi_w2, fi_b2, hfi, wt, fl, t);
  __syncthreads();
  const int lane = t & 63, wv = t >> 6;
  for (int p = 0; p < 4; p++) {
    int r = p * 4 + wv;
    float v = fl[r][lane];
    float m = v;
    for (int off = 32; off; off >>= 1) m = fmaxf(m, __shfl_xor(m, off));
    float e = expf(v - m);
    float s = e;
    for (int off = 32; off; off >>= 1) s += __shfl_xor(s, off);
    float fv = e / s;
    out_fi[(size_t)(b0 + r) * 64 + lane] = fv;
    fi_ws[(size_t)(b0 + r) * 64 + lane] = fv;
  }
}

// ---------------- G3: H2[8192,128] = relu([X|FI] @ sd_w1^T + b), K=576 ----------------
// BM=32, BN=64, BK=32, 256 threads, 2x4 per thread. Grid (256, 2).
__global__ __launch_bounds__(256) void g3_h2(
    const float* __restrict__ x, const float* __restrict__ fi,
    const float* __restrict__ sd_w1, const float* __restrict__ sd_b1,
    float* __restrict__ H2)
{
  __shared__ __align__(16) float Xs[32][36];   // [k][m], 36 pad (144B rows, 16B-mult)
  __shared__ __align__(16) float Ws[32][68];   // [k][n]
  const int t = threadIdx.x;
  const int bm0 = blockIdx.x * 32;
  const int bn0 = blockIdx.y * 64;
  const int tm = t & 15, tn = t >> 4;
  float acc[2][4];
#pragma unroll
  for (int i = 0; i < 2; i++)
#pragma unroll
    for (int j = 0; j < 4; j++) acc[i][j] = 0.f;

  for (int kc = 0; kc < 576; kc += 32) {
    __syncthreads();
    {
      int row = t >> 3, kq = t & 7;
      float4 v = (kc < 512)
          ? *(const float4*)(x + (size_t)(bm0 + row) * 512 + kc + kq * 4)
          : *(const float4*)(fi + (size_t)(bm0 + row) * 64 + (kc - 512) + kq * 4);
      Xs[kq * 4 + 0][row] = v.x; Xs[kq * 4 + 1][row] = v.y;
      Xs[kq * 4 + 2][row] = v.z; Xs[kq * 4 + 3][row] = v.w;
    }
#pragma unroll
    for (int s = 0; s < 2; s++) {
      int jj = t + s * 256;
      int col = jj >> 3, kq = jj & 7;
      float4 w = *(const float4*)(sd_w1 + (size_t)(bn0 + col) * 576 + kc + kq * 4);
      Ws[kq * 4 + 0][col] = w.x; Ws[kq * 4 + 1][col] = w.y;
      Ws[kq * 4 + 2][col] = w.z; Ws[kq * 4 + 3][col] = w.w;
    }
    __syncthreads();
#pragma unroll
    for (int kk = 0; kk < 32; kk++) {
      float2 xv = *(const float2*)&Xs[kk][tm * 2];
      float4 wv = *(const float4*)&Ws[kk][tn * 4];
      float xa[2] = {xv.x, xv.y};
      float wa[4] = {wv.x, wv.y, wv.z, wv.w};
#pragma unroll
      for (int i = 0; i < 2; i++)
#pragma unroll
        for (int j = 0; j < 4; j++) acc[i][j] += xa[i] * wa[j];
    }
  }
  const int cn = tn * 4;
  float bv[4];
#pragma unroll
  for (int j = 0; j < 4; j++) bv[j] = sd_b1[bn0 + cn + j];
#pragma unroll
  for (int i = 0; i < 2; i++) {
    float4 o;
    float v0 = acc[i][0] + bv[0]; o.x = v0 > 0.f ? v0 : 0.f;
    float v1 = acc[i][1] + bv[1]; o.y = v1 > 0.f ? v1 : 0.f;
    float v2 = acc[i][2] + bv[2]; o.z = v2 > 0.f ? v2 : 0.f;
    float v3 = acc[i][3] + bv[3]; o.w = v3 > 0.f ? v3 : 0.f;
    *(float4*)(H2 + (size_t)(bm0 + tm * 2 + i) * 128 + bn0 + cn) = o;
  }
}

// ---------------- G4: sd out-proj + sigmoid + top-16 + grouping ----------------
// 16 rows/block, 512 blocks. Selection arithmetic verbatim from old k1.
__global__ __launch_bounds__(256) void g4_sel(
    const float* __restrict__ H2, const float* __restrict__ costs,
    const float* __restrict__ sd_w2, const float* __restrict__ sd_b2,
    const float* __restrict__ unc_in,
    float* __restrict__ out_sp, float* __restrict__ out_mask,
    float* __restrict__ out_cost, int* __restrict__ rows_by_f,
    int* __restrict__ counts)
{
  __shared__ float hsd[16][129];
  __shared__ float wt_raw[64 * 33 + 16 * 64];
  __shared__ float uu[16];
  float (*wt)[33] = (float(*)[33])wt_raw;
  float (*fl)[64] = (float(*)[64])(wt_raw + 64 * 33);
  const int t = threadIdx.x;
  const int b0 = blockIdx.x * 16;
#pragma unroll
  for (int s = 0; s < 2; s++) {
    int jj = t + s * 256;
    int row = jj >> 5, f4 = jj & 31;
    float4 v = *(const float4*)(H2 + (size_t)(b0 + row) * 128 + f4 * 4);
    int c = f4 * 4;
    hsd[row][c] = v.x; hsd[row][c + 1] = v.y; hsd[row][c + 2] = v.z; hsd[row][c + 3] = v.w;
  }
  if (t < 16) uu[t] = unc_in[b0 + t];
  __syncthreads();
  mlp_out64(sd_w2, sd_b2, hsd, wt, fl, t);
  __syncthreads();
  const int lane = t & 63, wv = t >> 6;
  float cst = costs[lane];
  for (int p = 0; p < 4; p++) {
    int r = p * 4 + wv;
    float lg = fl[r][lane];
    float pr = 1.f / (1.f + expf(-lg));
    out_sp[(size_t)(b0 + r) * 64 + lane] = pr;
    fl[r][lane] = pr / (1.f + cst) * uu[r];
  }
  __syncthreads();
  for (int p = 0; p < 4; p++) {
    int r = p * 4 + wv;
    float a = fl[r][lane];
    float msk = 0.f;
    for (int it = 0; it < 16; it++) {
      float bv = a;
      int bi = lane;
      for (int off = 32; off; off >>= 1) {
        float ov = __shfl_xor(bv, off);
        int oi = __shfl_xor(bi, off);
        if (ov > bv || (ov == bv && oi < bi)) { bv = ov; bi = oi; }
      }
      if (lane == bi) {
        msk = 1.f;
        a = -__builtin_inff();
        int slot = atomicAdd(&counts[bi], 1);
        rows_by_f[bi * NB + slot] = ((b0 + r) << 4) | it;
      }
    }
    out_mask[(size_t)(b0 + r) * 64 + lane] = msk;
    float mc = msk * cst;
    for (int off = 32; off; off >>= 1) mc += __shfl_xor(mc, off);
    if (lane == 0) out_cost[b0 + r] = mc;
  }
}

// ---------------- K2: MFMA grouped encoder + qkv projection ----------------
// 32 rows per block, 4 waves. A-operands from padded LDS, B-operands from L2.
__global__ __launch_bounds__(256) void k2_mfma(
    const float* __restrict__ af, const __hip_bfloat16* __restrict__ encw_bf,
    const float* __restrict__ enc_b, const __hip_bfloat16* __restrict__ ipw_bf,
    const float* __restrict__ ipb, const int* __restrict__ rows_by_f,
    const int* __restrict__ counts, __hip_bfloat16* __restrict__ qkv)
{
  __shared__ __align__(16) __hip_bfloat16 af_lds[32][264];   // +8 pad: no bank alias
  __shared__ __align__(16) __hip_bfloat16 enc_lds[32][136];  // +8 pad
  __shared__ int ent[32];
  const int f = blockIdx.x;
  const int cnt = counts[f];
  const int base = blockIdx.y * 32;
  if (base >= cnt) return;
  const int t = threadIdx.x;
  const int nr = min(32, cnt - base);
  if (t < 32) ent[t] = (t < nr) ? rows_by_f[f * NB + base + t] : -1;
  __syncthreads();
  { // gather 32 rows of available_features[f], convert fp32->bf16
    int r = t >> 3, c0 = (t & 7) * 32;
    int e = ent[r];
    if (e >= 0) {
      const float* src = af + ((size_t)f * NB + (size_t)(e >> 4)) * 256 + c0;
#pragma unroll
      for (int q = 0; q < 8; q++) {
        float4 v = *(const float4*)(src + q * 4);
        union { __hip_bfloat16 h[4]; short4 s; } u;
        u.h[0] = __float2bfloat16(v.x); u.h[1] = __float2bfloat16(v.y);
        u.h[2] = __float2bfloat16(v.z); u.h[3] = __float2bfloat16(v.w);
        *(short4*)&af_lds[r][c0 + q * 4] = u.s;
      }
    } else {
      short4 z = {0, 0, 0, 0};
#pragma unroll
      for (int q = 0; q < 8; q++) *(short4*)&af_lds[r][c0 + q * 4] = z;
    }
  }
  __syncthreads();
  const int lane = t & 63, wv = t >> 6;
  const int lr = lane & 15, quad = lane >> 4;
  const int r0 = (wv & 1) * 16;          // row half
  // ---- GEMM1: enc[32x128] = af[32x256] @ enc_w[f][128x256]^T ----
  const __hip_bfloat16* wf = encw_bf + (size_t)f * 32768;
  const int c0 = (wv >> 1) * 64;         // col half (4 tiles of 16)
  f32x4 acc[4];
#pragma unroll
  for (int ct = 0; ct < 4; ct++) acc[ct] = (f32x4){0.f, 0.f, 0.f, 0.f};
#pragma unroll
  for (int ks = 0; ks < 8; ks++) {
    short8 a = *(const short8*)&af_lds[r0 + lr][ks * 32 + quad * 8];
#pragma unroll
    for (int ct = 0; ct < 4; ct++) {
      short8 b = *(const short8*)(wf + (size_t)(c0 + ct * 16 + lr) * 256 + ks * 32 + quad * 8);
      acc[ct] = __builtin_amdgcn_mfma_f32_16x16x32_bf16(a, b, acc[ct], 0, 0, 0);
    }
  }
#pragma unroll
  for (int ct = 0; ct < 4; ct++) {
    int col = c0 + ct * 16 + lr;
    float bv = enc_b[f * 128 + col];
#pragma unroll
    for (int rr = 0; rr < 4; rr++)
      enc_lds[r0 + quad * 4 + rr][col] = __float2bfloat16(acc[ct][rr] + bv);
  }
  __syncthreads();
  // ---- GEMM2: qkv[32x384] = enc[32x128] @ in_proj_w[384x128]^T ----
  short8 a2[4];
#pragma unroll
  for (int ks = 0; ks < 4; ks++)
    a2[ks] = *(const short8*)&enc_lds[r0 + lr][ks * 32 + quad * 8];
  const int o0 = (wv >> 1) * 192;        // 12 tiles of 16
#pragma unroll
  for (int ot = 0; ot < 12; ot++) {
    int ob = o0 + ot * 16;
    f32x4 c2 = (f32x4){0.f, 0.f, 0.f, 0.f};
#pragma unroll
    for (int ks = 0; ks < 4; ks++) {
      short8 b = *(const short8*)(ipw_bf + (size_t)(ob + lr) * 128 + ks * 32 + quad * 8);
      c2 = __builtin_amdgcn_mfma_f32_16x16x32_bf16(a2[ks], b, c2, 0, 0, 0);
    }
    int col = ob + lr;
    float bv = ipb[col];
#pragma unroll
    for (int rr = 0; rr < 4; rr++) {
      int e = ent[r0 + quad * 4 + rr];
      if (e >= 0)
        qkv[((size_t)(e >> 4) * 16 + (size_t)(e & 15)) * 384 + col] =
            __float2bfloat16(c2[rr] + bv);
    }
  }
}

// ---------------- K3: collapsed attention -> mean_ctx [B,128] ----------------
__global__ __launch_bounds__(192) void k3_attn(
    const __hip_bfloat16* __restrict__ qkv_sel, const float* __restrict__ ipb,
    float* __restrict__ mean_ctx)
{
  __shared__ float qt[384][17];
  __shared__ float sm[8][17][18];
  __shared__ float cw[8][18];
  const int b = blockIdx.x, t = threadIdx.x;
  const __hip_bfloat16* src = qkv_sel + (size_t)b * 16 * 384;
  for (int j = 0; j < 16; j++)
    for (int c = t; c < 384; c += 192)
      qt[c][j] = __bfloat162float(src[j * 384 + c]);
  for (int c = t; c < 384; c += 192) qt[c][16] = ipb[c];
  __syncthreads();
  if (t < 136) {
    int h = t / 17, qi = t % 17;
    const int qb = h * 16, kbx = 128 + h * 16;
    float qv[16];
#pragma unroll
    for (int d = 0; d < 16; d++) qv[d] = qt[qb + d][qi];
    for (int ki = 0; ki < 17; ki++) {
      float s = 0.f;
#pragma unroll
      for (int d = 0; d < 16; d++) s += qv[d] * qt[kbx + d][ki];
      sm[h][qi][ki] = s * 0.25f;
    }
  }
  __syncthreads();
  if (t < 136) {
    int h = t / 17, qi = t % 17;
    float m = -__builtin_inff();
    for (int ki = 0; ki < 17; ki++) m = fmaxf(m, sm[h][qi][ki]);
    float e[17], den = 0.f;
#pragma unroll
    for (int ki = 0; ki < 17; ki++) {
      e[ki] = expf(sm[h][qi][ki] - m);
      den += (ki == 16 ? 48.f : 1.f) * e[ki];
    }
    float mult = (qi == 16) ? 48.f : 1.f;
    float inv = mult / den;
#pragma unroll
    for (int ki = 0; ki < 17; ki++) sm[h][qi][ki] = e[ki] * inv;
  }
  __syncthreads();
  if (t < 136) {
    int h = t / 17, ki = t % 17;
    float s = 0.f;
    for (int qi = 0; qi < 17; qi++) s += sm[h][qi][ki];
    cw[h][ki] = s * ((ki == 16) ? 48.f : 1.f) * (1.f / 64.f);
  }
  __syncthreads();
  if (t < 128) {
    int h = t >> 4, d = t & 15;
    int vb = 256 + h * 16 + d;
    float s = 0.f;
#pragma unroll
    for (int ki = 0; ki < 17; ki++) s += cw[h][ki] * qt[vb][ki];
    mean_ctx[(size_t)b * 128 + t] = s;
  }
}

// ---------------- K4: enhanced_x = x + mean_ctx @ M^T + b' ----------------
__global__ __launch_bounds__(256) void k4_out(
    const float* __restrict__ x, const float* __restrict__ mc,
    const float* __restrict__ M, const float* __restrict__ bf,
    float* __restrict__ out)
{
  __shared__ float ms[32][128];
  __shared__ float wt[128][65];
  const int t = threadIdx.x;
  const int b0 = blockIdx.x * 32;
  {
    int r = t >> 3, c0 = (t & 7) * 16;
    const float* s = mc + (size_t)(b0 + r) * 128 + c0;
#pragma unroll
    for (int q = 0; q < 16; q++) ms[r][c0 + q] = s[q];
  }
  const int i = t & 127, rg = t >> 7;
  const int il = t >> 1, kb = (t & 1) * 32;
  for (int oc = 0; oc < 4; oc++) {
    float acc[16];
#pragma unroll
    for (int rr = 0; rr < 16; rr++) acc[rr] = 0.f;
    for (int kc = 0; kc < 128; kc += 64) {
      __syncthreads();
      const float* wr = M + (oc * 128 + il) * 128 + kc + kb;
#pragma unroll
      for (int q = 0; q < 32; q++) wt[il][kb + q] = wr[q];
      __syncthreads();
#pragma unroll
      for (int kk = 0; kk < 64; kk++) {
        float w = wt[i][kk];
#pragma unroll
        for (int rr = 0; rr < 16; rr++) acc[rr] += w * ms[rg * 16 + rr][kc + kk];
      }
    }
    float bb = bf[oc * 128 + i];
#pragma unroll
    for (int rr = 0; rr < 16; rr++) {
      size_t idx = (size_t)(b0 + rg * 16 + rr) * 512 + oc * 128 + i;
      out[idx] = x[idx] + acc[rr] + bb;
    }
  }
}

// ---------------- host ----------------
extern "C" void kernel_launch(void* const* d_in, const int* in_sizes, int n_in,
                              void* d_out, int out_size, void* d_ws, size_t ws_size,
                              hipStream_t stream)
{
  const float* x      = (const float*)d_in[0];
  const float* af     = (const float*)d_in[1];
  const float* costs  = (const float*)d_in[2];
  const float* ue_w1  = (const float*)d_in[3];
  const float* ue_b1  = (const float*)d_in[4];
  const float* ue_w2  = (const float*)d_in[5];
  const float* ue_b2  = (const float*)d_in[6];
  const float* fi_w1  = (const float*)d_in[7];
  const float* fi_b1  = (const float*)d_in[8];
  const float* fi_w2  = (const float*)d_in[9];
  const float* fi_b2  = (const float*)d_in[10];
  const float* sd_w1  = (const float*)d_in[11];
  const float* sd_b1  = (const float*)d_in[12];
  const float* sd_w2  = (const float*)d_in[13];
  const float* sd_b2  = (const float*)d_in[14];
  const float* enc_w  = (const float*)d_in[15];
  const float* enc_b  = (const float*)d_in[16];
  const float* ipw    = (const float*)d_in[17];
  const float* ipb    = (const float*)d_in[18];
  const float* opjw   = (const float*)d_in[19];
  const float* opjb   = (const float*)d_in[20];
  const float* op_w   = (const float*)d_in[21];
  const float* op_b   = (const float*)d_in[22];

  float* out = (float*)d_out;
  float* out_enh  = out;                    // [B,512]
  float* out_unc  = out + 4194304;          // [B,1]
  float* out_fi   = out_unc + 8192;         // [B,64]
  float* out_sp   = out_fi + 524288;        // [B,64]
  float* out_mask = out_sp + 524288;        // [B,64]
  float* out_cost = out_mask + 524288;      // [B]

  char* ws = (char*)d_ws;
  __hip_bfloat16* qkv     = (__hip_bfloat16*)ws;                  // 100,663,296 B
  // G1-G4 scratch aliased into low qkv region (dead before K2 writes qkv):
  float*          H1      = (float*)ws;                           // 8 MB [8192,256]
  float*          H2      = (float*)(ws + 8388608);               // 4 MB [8192,128]
  float*          FIws    = (float*)(ws + 12582912);              // 2 MB [8192,64]
  __hip_bfloat16* encw_bf = (__hip_bfloat16*)(ws + 100663296);    // 4,194,304 B (K0b->K2)
  float*          mc      = (float*)(ws + 100663296);             // alias: K3->K4 (4 MB)
  __hip_bfloat16* ipw_bf  = (__hip_bfloat16*)(ws + 104857600);    // 98,304 B
  float*          M       = (float*)(ws + 104955904);             // 262,144 B
  float*          bfv     = (float*)(ws + 105218048);             // 2,048 B
  int*            rows    = (int*)(ws + 105220096);               // 2,097,152 B
  int*            counts  = (int*)(ws + 107317248);               // 256 B

  hipMemsetAsync(counts, 0, 64 * sizeof(int), stream);
  k0_fuse<<<257, 256, 0, stream>>>(op_w, opjw, opjb, op_b, M, bfv);
  k0b_cvt<<<2096, 256, 0, stream>>>(enc_w, ipw, encw_bf, ipw_bf);
  g1_h1<<<dim3(128, 4), 256, 0, stream>>>(x, ue_w1, ue_b1, fi_w1, fi_b1, H1);
  g2_fi<<<512, 256, 0, stream>>>(H1, ue_w2, ue_b2, fi_w2, fi_b2,
                                 out_unc, out_fi, FIws);
  g3_h2<<<dim3(256, 2), 256, 0, stream>>>(x, FIws, sd_w1, sd_b1, H2);
  g4_sel<<<512, 256, 0, stream>>>(H2, costs, sd_w2, sd_b2, out_unc,
                                  out_sp, out_mask, out_cost, rows, counts);
  k2_mfma<<<dim3(64, 256), 256, 0, stream>>>(af, encw_bf, enc_b, ipw_bf, ipb,
                                             rows, counts, qkv);
  k3_attn<<<8192, 192, 0, stream>>>(qkv, ipb, mc);
  k4_out<<<256, 256, 0, stream>>>(x, mc, M, bfv, out_enh);
}

// Round 2
// 1746.468 us; speedup vs baseline: 1.3386x; 1.2629x over previous
//
#include <hip/hip_runtime.h>
#include <hip/hip_bf16.h>

// ActivePerceptionLayer: B=8192, IN=512, D=256, F=64, A=128, H=8, HD=16, BUDGET=16
//
// Pipeline:
//  K0 : fuse M = op_w @ out_proj_w [512,128], b' = op_b + op_w @ out_proj_b
//  K0b: convert enc_w + in_proj_w to bf16
//  G1 : SGEMM H1[8192,256] = relu(X @ [ue_w1;fi_w1]^T + b)   (fp32, bit-exact chain)
//  G2 : epilogue: uncertainty + fi out-proj + softmax -> out_unc/out_fi/FIws
//  G3 : SGEMM H2[8192,128] = relu([X | FI] @ sd_w1^T + b)    (K=576 concat)
//  G4 : sd out-proj + sigmoid + top-16 select + mask/cost + feature grouping
//  K2a: grouped encoder GEMM, 128 rows/block, A+B staged in LDS fragment-order;
//       ENC[slot,128] bf16 stashed in the V-strip of qkv rows (qkv+slot*768+512)
//  K2b: dense qkv[131072,384] = ENC @ in_proj_w^T + b; per block 128 rows x 384
//       cols, A+B in LDS, LDS-transpose epilogue -> coalesced row stores
//       (overwrites the ENC stash it just consumed; per-block read-then-write)
//  K3 : collapsed attention (48 masked positions share qkv=in_proj_b -> 17x17)
//  K4 : enhanced_x = x + mean_ctx @ M^T + b'
//
// Old fused k2_mfma was 674us at MfmaUtil 1.25% / VALUBusy 1.9% (B-operands
// fetched per-MFMA from L2 as 16-line scattered wave loads, VGPR=44 -> no
// prefetch). K2a/K2b keep the exact same MFMA shapes, k-ascending accumulation
// order, conversion points and bias adds -> outputs bit-identical.
//
// Workspace (~107.3 MB): qkv bf16 (low 14.7MB aliased by H1/H2/FI during G1-G4;
//   V-strips alias ENC stash during K2a->K2b) | enc_w_bf 4MB (aliased by
//   mean_ctx after K2a) | ipw_bf | M | b' | rows_by_f | counts

#define NB 8192

typedef __attribute__((ext_vector_type(8))) short short8;
typedef __attribute__((ext_vector_type(4))) float f32x4;

// ---------------- K0: fold out_proj and output_projection ----------------
__global__ __launch_bounds__(256) void k0_fuse(
    const float* __restrict__ op_w, const float* __restrict__ out_proj_w,
    const float* __restrict__ out_proj_b, const float* __restrict__ op_b,
    float* __restrict__ M, float* __restrict__ bf)
{
  int g = blockIdx.x;
  if (g < 256) {
    int t = g * 256 + threadIdx.x;       // 0..65535
    int i = t >> 7, j = t & 127;         // M[i][j] = sum_k op_w[i][k]*out_proj_w[k][j]
    float acc = 0.f;
    for (int k = 0; k < 128; k++) acc += op_w[i * 128 + k] * out_proj_w[k * 128 + j];
    M[i * 128 + j] = acc;
  } else {
    for (int ii = threadIdx.x; ii < 512; ii += 256) {
      float acc = op_b[ii];
      for (int k = 0; k < 128; k++) acc += op_w[ii * 128 + k] * out_proj_b[k];
      bf[ii] = acc;
    }
  }
}

// ---------------- K0b: fp32 -> bf16 weight conversion ----------------
__global__ __launch_bounds__(256) void k0b_cvt(
    const float* __restrict__ encw, const float* __restrict__ ipw,
    __hip_bfloat16* __restrict__ encw_bf, __hip_bfloat16* __restrict__ ipw_bf)
{
  const int NE = 64 * 128 * 256;            // 2,097,152 (mult of 4)
  const int NT4 = (NE + 384 * 128) / 4;     // 536,576 groups of 4
  int i4 = blockIdx.x * 256 + threadIdx.x;
  if (i4 >= NT4) return;
  int i = i4 * 4;
  float4 v = (i < NE) ? *(const float4*)(encw + i)
                      : *(const float4*)(ipw + (i - NE));
  union { __hip_bfloat16 h[4]; short4 s; } u;
  u.h[0] = __float2bfloat16(v.x); u.h[1] = __float2bfloat16(v.y);
  u.h[2] = __float2bfloat16(v.z); u.h[3] = __float2bfloat16(v.w);
  if (i < NE) *(short4*)(encw_bf + i) = u.s;
  else        *(short4*)(ipw_bf + (i - NE)) = u.s;
}

// ---------------- shared epilogue helper (verbatim arithmetic) ----------------
__device__ __forceinline__ void mlp_out64(const float* __restrict__ w2,
                                          const float* __restrict__ b2,
                                          const float (*h1)[129], float (*wt2)[33],
                                          float (*fl)[64], int t)
{
  const int o = t & 63, rg4 = t >> 6;
  const int ol = t >> 2, kb = (t & 3) * 8;
  float acc[4];
#pragma unroll
  for (int rr = 0; rr < 4; rr++) acc[rr] = 0.f;
  for (int kc = 0; kc < 128; kc += 32) {
    __syncthreads();
    const float* wr = w2 + ol * 128 + kc + kb;
#pragma unroll
    for (int q = 0; q < 8; q++) wt2[ol][kb + q] = wr[q];
    __syncthreads();
#pragma unroll
    for (int kk = 0; kk < 32; kk++) {
      float w = wt2[o][kk];
#pragma unroll
      for (int rr = 0; rr < 4; rr++)
        acc[rr] += w * h1[rg4 * 4 + rr][kc + kk];
    }
  }
  float bv = b2[o];
#pragma unroll
  for (int rr = 0; rr < 4; rr++) fl[rg4 * 4 + rr][o] = acc[rr] + bv;
}

// ---------------- G1: H1[8192,256] = relu(X @ [ue_w1;fi_w1]^T + b) ----------------
__global__ __launch_bounds__(256) void g1_h1(
    const float* __restrict__ x,
    const float* __restrict__ ue_w1, const float* __restrict__ ue_b1,
    const float* __restrict__ fi_w1, const float* __restrict__ fi_b1,
    float* __restrict__ H1)
{
  __shared__ __align__(16) float Xs[32][68];
  __shared__ __align__(16) float Ws[32][68];
  const int t = threadIdx.x;
  const int bm0 = blockIdx.x * 64;
  const int bn0 = blockIdx.y * 64;             // 0,64 -> ue ; 128,192 -> fi
  const float* __restrict__ W    = (bn0 < 128) ? ue_w1 : fi_w1;
  const float* __restrict__ bias = (bn0 < 128) ? ue_b1 : fi_b1;
  const int wr0 = bn0 & 127;
  const int tm = t & 15, tn = t >> 4;
  float acc[4][4];
#pragma unroll
  for (int i = 0; i < 4; i++)
#pragma unroll
    for (int j = 0; j < 4; j++) acc[i][j] = 0.f;

  for (int kc = 0; kc < 512; kc += 32) {
    __syncthreads();
#pragma unroll
    for (int s = 0; s < 2; s++) {
      int jj = t + s * 256;
      int row = jj >> 3, kq = jj & 7;
      float4 v = *(const float4*)(x + (size_t)(bm0 + row) * 512 + kc + kq * 4);
      Xs[kq * 4 + 0][row] = v.x; Xs[kq * 4 + 1][row] = v.y;
      Xs[kq * 4 + 2][row] = v.z; Xs[kq * 4 + 3][row] = v.w;
      float4 w = *(const float4*)(W + (size_t)(wr0 + row) * 512 + kc + kq * 4);
      Ws[kq * 4 + 0][row] = w.x; Ws[kq * 4 + 1][row] = w.y;
      Ws[kq * 4 + 2][row] = w.z; Ws[kq * 4 + 3][row] = w.w;
    }
    __syncthreads();
#pragma unroll
    for (int kk = 0; kk < 32; kk++) {
      float4 xv = *(const float4*)&Xs[kk][tm * 4];
      float4 wv = *(const float4*)&Ws[kk][tn * 4];
      float xa[4] = {xv.x, xv.y, xv.z, xv.w};
      float wa[4] = {wv.x, wv.y, wv.z, wv.w};
#pragma unroll
      for (int i = 0; i < 4; i++)
#pragma unroll
        for (int j = 0; j < 4; j++) acc[i][j] += xa[i] * wa[j];
    }
  }
  const int rm = bm0 + tm * 4;
  const int cn = tn * 4;
  float bv[4];
#pragma unroll
  for (int j = 0; j < 4; j++) bv[j] = bias[wr0 + cn + j];
#pragma unroll
  for (int i = 0; i < 4; i++) {
    float4 o;
    float v0 = acc[i][0] + bv[0]; o.x = v0 > 0.f ? v0 : 0.f;
    float v1 = acc[i][1] + bv[1]; o.y = v1 > 0.f ? v1 : 0.f;
    float v2 = acc[i][2] + bv[2]; o.z = v2 > 0.f ? v2 : 0.f;
    float v3 = acc[i][3] + bv[3]; o.w = v3 > 0.f ? v3 : 0.f;
    *(float4*)(H1 + (size_t)(rm + i) * 256 + bn0 + cn) = o;
  }
}

// ---------------- G2: uncertainty + fi out-proj + softmax ----------------
__global__ __launch_bounds__(256) void g2_fi(
    const float* __restrict__ H1,
    const float* __restrict__ ue_w2, const float* __restrict__ ue_b2,
    const float* __restrict__ fi_w2, const float* __restrict__ fi_b2,
    float* __restrict__ out_unc, float* __restrict__ out_fi,
    float* __restrict__ fi_ws)
{
  __shared__ float hue[16][129];
  __shared__ float hfi[16][129];
  __shared__ float wt_raw[64 * 33 + 16 * 64];
  float (*wt)[33] = (float(*)[33])wt_raw;
  float (*fl)[64] = (float(*)[64])(wt_raw + 64 * 33);
  const int t = threadIdx.x;
  const int b0 = blockIdx.x * 16;
#pragma unroll
  for (int s = 0; s < 4; s++) {
    int jj = t + s * 256;
    int row = jj >> 6, f4 = jj & 63;
    float4 v = *(const float4*)(H1 + (size_t)(b0 + row) * 256 + f4 * 4);
    if (f4 < 32) {
      int c = f4 * 4;
      hue[row][c] = v.x; hue[row][c + 1] = v.y; hue[row][c + 2] = v.z; hue[row][c + 3] = v.w;
    } else {
      int c = (f4 - 32) * 4;
      hfi[row][c] = v.x; hfi[row][c + 1] = v.y; hfi[row][c + 2] = v.z; hfi[row][c + 3] = v.w;
    }
  }
  __syncthreads();
  if (t < 16) {
    float a = ue_b2[0];
    for (int k = 0; k < 128; k++) a += ue_w2[k] * hue[t][k];
    float u = 1.f / (1.f + expf(-a));
    out_unc[b0 + t] = u;
  }
  mlp_out64(fi_w2, fi_b2, hfi, wt, fl, t);
  __syncthreads();
  const int lane = t & 63, wv = t >> 6;
  for (int p = 0; p < 4; p++) {
    int r = p * 4 + wv;
    float v = fl[r][lane];
    float m = v;
    for (int off = 32; off; off >>= 1) m = fmaxf(m, __shfl_xor(m, off));
    float e = expf(v - m);
    float s = e;
    for (int off = 32; off; off >>= 1) s += __shfl_xor(s, off);
    float fv = e / s;
    out_fi[(size_t)(b0 + r) * 64 + lane] = fv;
    fi_ws[(size_t)(b0 + r) * 64 + lane] = fv;
  }
}

// ---------------- G3: H2[8192,128] = relu([X|FI] @ sd_w1^T + b), K=576 ----------------
__global__ __launch_bounds__(256) void g3_h2(
    const float* __restrict__ x, const float* __restrict__ fi,
    const float* __restrict__ sd_w1, const float* __restrict__ sd_b1,
    float* __restrict__ H2)
{
  __shared__ __align__(16) float Xs[32][36];
  __shared__ __align__(16) float Ws[32][68];
  const int t = threadIdx.x;
  const int bm0 = blockIdx.x * 32;
  const int bn0 = blockIdx.y * 64;
  const int tm = t & 15, tn = t >> 4;
  float acc[2][4];
#pragma unroll
  for (int i = 0; i < 2; i++)
#pragma unroll
    for (int j = 0; j < 4; j++) acc[i][j] = 0.f;

  for (int kc = 0; kc < 576; kc += 32) {
    __syncthreads();
    {
      int row = t >> 3, kq = t & 7;
      float4 v = (kc < 512)
          ? *(const float4*)(x + (size_t)(bm0 + row) * 512 + kc + kq * 4)
          : *(const float4*)(fi + (size_t)(bm0 + row) * 64 + (kc - 512) + kq * 4);
      Xs[kq * 4 + 0][row] = v.x; Xs[kq * 4 + 1][row] = v.y;
      Xs[kq * 4 + 2][row] = v.z; Xs[kq * 4 + 3][row] = v.w;
    }
#pragma unroll
    for (int s = 0; s < 2; s++) {
      int jj = t + s * 256;
      int col = jj >> 3, kq = jj & 7;
      float4 w = *(const float4*)(sd_w1 + (size_t)(bn0 + col) * 576 + kc + kq * 4);
      Ws[kq * 4 + 0][col] = w.x; Ws[kq * 4 + 1][col] = w.y;
      Ws[kq * 4 + 2][col] = w.z; Ws[kq * 4 + 3][col] = w.w;
    }
    __syncthreads();
#pragma unroll
    for (int kk = 0; kk < 32; kk++) {
      float2 xv = *(const float2*)&Xs[kk][tm * 2];
      float4 wv = *(const float4*)&Ws[kk][tn * 4];
      float xa[2] = {xv.x, xv.y};
      float wa[4] = {wv.x, wv.y, wv.z, wv.w};
#pragma unroll
      for (int i = 0; i < 2; i++)
#pragma unroll
        for (int j = 0; j < 4; j++) acc[i][j] += xa[i] * wa[j];
    }
  }
  const int cn = tn * 4;
  float bv[4];
#pragma unroll
  for (int j = 0; j < 4; j++) bv[j] = sd_b1[bn0 + cn + j];
#pragma unroll
  for (int i = 0; i < 2; i++) {
    float4 o;
    float v0 = acc[i][0] + bv[0]; o.x = v0 > 0.f ? v0 : 0.f;
    float v1 = acc[i][1] + bv[1]; o.y = v1 > 0.f ? v1 : 0.f;
    float v2 = acc[i][2] + bv[2]; o.z = v2 > 0.f ? v2 : 0.f;
    float v3 = acc[i][3] + bv[3]; o.w = v3 > 0.f ? v3 : 0.f;
    *(float4*)(H2 + (size_t)(bm0 + tm * 2 + i) * 128 + bn0 + cn) = o;
  }
}

// ---------------- G4: sd out-proj + sigmoid + top-16 + grouping ----------------
__global__ __launch_bounds__(256) void g4_sel(
    const float* __restrict__ H2, const float* __restrict__ costs,
    const float* __restrict__ sd_w2, const float* __restrict__ sd_b2,
    const float* __restrict__ unc_in,
    float* __restrict__ out_sp, float* __restrict__ out_mask,
    float* __restrict__ out_cost, int* __restrict__ rows_by_f,
    int* __restrict__ counts)
{
  __shared__ float hsd[16][129];
  __shared__ float wt_raw[64 * 33 + 16 * 64];
  __shared__ float uu[16];
  float (*wt)[33] = (float(*)[33])wt_raw;
  float (*fl)[64] = (float(*)[64])(wt_raw + 64 * 33);
  const int t = threadIdx.x;
  const int b0 = blockIdx.x * 16;
#pragma unroll
  for (int s = 0; s < 2; s++) {
    int jj = t + s * 256;
    int row = jj >> 5, f4 = jj & 31;
    float4 v = *(const float4*)(H2 + (size_t)(b0 + row) * 128 + f4 * 4);
    int c = f4 * 4;
    hsd[row][c] = v.x; hsd[row][c + 1] = v.y; hsd[row][c + 2] = v.z; hsd[row][c + 3] = v.w;
  }
  if (t < 16) uu[t] = unc_in[b0 + t];
  __syncthreads();
  mlp_out64(sd_w2, sd_b2, hsd, wt, fl, t);
  __syncthreads();
  const int lane = t & 63, wv = t >> 6;
  float cst = costs[lane];
  for (int p = 0; p < 4; p++) {
    int r = p * 4 + wv;
    float lg = fl[r][lane];
    float pr = 1.f / (1.f + expf(-lg));
    out_sp[(size_t)(b0 + r) * 64 + lane] = pr;
    fl[r][lane] = pr / (1.f + cst) * uu[r];
  }
  __syncthreads();
  for (int p = 0; p < 4; p++) {
    int r = p * 4 + wv;
    float a = fl[r][lane];
    float msk = 0.f;
    for (int it = 0; it < 16; it++) {
      float bv = a;
      int bi = lane;
      for (int off = 32; off; off >>= 1) {
        float ov = __shfl_xor(bv, off);
        int oi = __shfl_xor(bi, off);
        if (ov > bv || (ov == bv && oi < bi)) { bv = ov; bi = oi; }
      }
      if (lane == bi) {
        msk = 1.f;
        a = -__builtin_inff();
        int slot = atomicAdd(&counts[bi], 1);
        rows_by_f[bi * NB + slot] = ((b0 + r) << 4) | it;
      }
    }
    out_mask[(size_t)(b0 + r) * 64 + lane] = msk;
    float mc = msk * cst;
    for (int off = 32; off; off >>= 1) mc += __shfl_xor(mc, off);
    if (lane == 0) out_cost[b0 + r] = mc;
  }
}

// ---------------- K2a: grouped encoder GEMM (128 rows/block) ----------------
// ENC[slot,0..127] = cvt_bf16( af_rows[128x256]_bf16 @ enc_w[f]^T + enc_b )
// stashed at qkv + slot*384 + 256 (elems) = the V-strip, overwritten by K2b.
// A and B staged in LDS in MFMA-fragment order: chunk(m|ct, ks) = 64 lanes x 16B,
// so ds_read_b128 is fully contiguous (conflict-free).
__global__ __launch_bounds__(256, 1) void k2a_enc(
    const float* __restrict__ af, const __hip_bfloat16* __restrict__ encw_bf,
    const float* __restrict__ enc_b, const int* __restrict__ rows_by_f,
    const int* __restrict__ counts, __hip_bfloat16* __restrict__ qkv)
{
  __shared__ __align__(16) __hip_bfloat16 smA[32768];  // ((m*8+ks)*64+lane)*8
  __shared__ __align__(16) __hip_bfloat16 smB[32768];  // ((ct*8+ks)*64+lane)*8
  __shared__ int ent[128];
  const int f = blockIdx.x;
  const int cnt = counts[f];
  const int base = blockIdx.y * 128;
  if (base >= cnt) return;
  const int t = threadIdx.x;
  const int nr = min(128, cnt - base);
  if (t < 128) ent[t] = (t < nr) ? rows_by_f[f * NB + base + t] : -1;
  __syncthreads();
  const int lane = t & 63, wv = t >> 6;
  const int lr = lane & 15, quad = lane >> 4;
  // ---- stage A: gather af rows, cvt bf16, fragment layout (2 thr/row) ----
  {
    const int r = t >> 1, kh = t & 1;          // local row, k-half (128 floats)
    const int m = r >> 4, lrr = r & 15;
    const int e = ent[r];
    const float* src = nullptr;
    if (e >= 0) src = af + ((size_t)f * NB + (size_t)(e >> 4)) * 256 + kh * 128;
#pragma unroll
    for (int g = 0; g < 4; g++) {
      float4 v[8];
      if (e >= 0) {
#pragma unroll
        for (int q = 0; q < 8; q++) v[q] = *(const float4*)(src + g * 32 + q * 4);
      } else {
#pragma unroll
        for (int q = 0; q < 8; q++) v[q] = make_float4(0.f, 0.f, 0.f, 0.f);
      }
      const int ks = kh * 4 + g;
#pragma unroll
      for (int u = 0; u < 4; u++) {
        union { __hip_bfloat16 h[8]; short8 s8; } p;
        float4 a0 = v[u * 2], a1 = v[u * 2 + 1];
        p.h[0] = __float2bfloat16(a0.x); p.h[1] = __float2bfloat16(a0.y);
        p.h[2] = __float2bfloat16(a0.z); p.h[3] = __float2bfloat16(a0.w);
        p.h[4] = __float2bfloat16(a1.x); p.h[5] = __float2bfloat16(a1.y);
        p.h[6] = __float2bfloat16(a1.z); p.h[7] = __float2bfloat16(a1.w);
        *(short8*)&smA[(((m * 8 + ks) * 64) + u * 16 + lrr) * 8] = p.s8;
      }
    }
  }
  // ---- stage B: enc_w[f] 64KB -> fragment layout (16 chunks/wave) ----
  {
    const __hip_bfloat16* wf = encw_bf + (size_t)f * 32768;
#pragma unroll
    for (int s = 0; s < 16; s++) {
      const int i = wv * 16 + s, ct = i >> 3, ks = i & 7;
      short8 b = *(const short8*)(wf + (size_t)(ct * 16 + lr) * 256 + ks * 32 + quad * 8);
      *(short8*)&smB[((ct * 8 + ks) * 64 + lane) * 8] = b;
    }
  }
  __syncthreads();
  // ---- MFMA: C[128x128]; wave owns m-tiles {2wv, 2wv+1} x all 8 ct ----
  f32x4 acc[2][8];
#pragma unroll
  for (int i = 0; i < 2; i++)
#pragma unroll
    for (int ct = 0; ct < 8; ct++) acc[i][ct] = (f32x4){0.f, 0.f, 0.f, 0.f};
#pragma unroll
  for (int ks = 0; ks < 8; ks++) {
    short8 a0 = *(const short8*)&smA[(((2 * wv) * 8 + ks) * 64 + lane) * 8];
    short8 a1 = *(const short8*)&smA[(((2 * wv + 1) * 8 + ks) * 64 + lane) * 8];
#pragma unroll
    for (int ct = 0; ct < 8; ct++) {
      short8 b = *(const short8*)&smB[((ct * 8 + ks) * 64 + lane) * 8];
      acc[0][ct] = __builtin_amdgcn_mfma_f32_16x16x32_bf16(a0, b, acc[0][ct], 0, 0, 0);
      acc[1][ct] = __builtin_amdgcn_mfma_f32_16x16x32_bf16(a1, b, acc[1][ct], 0, 0, 0);
    }
  }
  __syncthreads();                       // all waves done with smA/smB
  // ---- epilogue: +bias, cvt, LDS transpose [128][136], coalesced stash ----
  __hip_bfloat16* C = smA;               // 128*136 = 17408 elems <= 32768
#pragma unroll
  for (int i = 0; i < 2; i++) {
    const int mt = 2 * wv + i;
#pragma unroll
    for (int ct = 0; ct < 8; ct++) {
      const int col = ct * 16 + lr;
      const float bv = enc_b[f * 128 + col];
#pragma unroll
      for (int rr = 0; rr < 4; rr++)
        C[(mt * 16 + quad * 4 + rr) * 136 + col] = __float2bfloat16(acc[i][ct][rr] + bv);
    }
  }
  __syncthreads();
  {
    const int r = t >> 1, h = t & 1;
    const int e = ent[r];
    if (e >= 0) {
      const size_t slot = (size_t)(e >> 4) * 16 + (size_t)(e & 15);
      __hip_bfloat16* dst = qkv + slot * 384 + 256 + h * 64;
      const __hip_bfloat16* sp = &C[r * 136 + h * 64];
#pragma unroll
      for (int q = 0; q < 8; q++)
        *(short8*)(dst + q * 8) = *(const short8*)(sp + q * 8);
    }
  }
}

// ---------------- K2b: dense qkv[131072,384] = ENC @ ipw^T + ipb ----------------
// Per block: 128 slot-rows x all 384 cols, K=128. A read from the ENC stash
// (same rows this block overwrites -> read-before-write within block).
__global__ __launch_bounds__(256, 1) void k2b_qkv(
    const __hip_bfloat16* __restrict__ ipw_bf, const float* __restrict__ ipb,
    __hip_bfloat16* __restrict__ qkv)
{
  __shared__ __align__(16) __hip_bfloat16 sm2[65536];  // A 16384 | B 49152 elems
  __hip_bfloat16* smA = sm2;                 // ((m*4+ks)*64+lane)*8
  __hip_bfloat16* smB = sm2 + 16384;         // ((ct*4+ks)*64+lane)*8
  const int t = threadIdx.x;
  const int lane = t & 63, wv = t >> 6;
  const int lr = lane & 15, quad = lane >> 4;
  const size_t bm0 = (size_t)blockIdx.x * 128;
  // ---- stage A from ENC stash (8 chunks/wave) ----
#pragma unroll
  for (int s = 0; s < 8; s++) {
    const int i = wv * 8 + s, m = i >> 2, ks = i & 3;
    const __hip_bfloat16* src = qkv + (bm0 + m * 16 + lr) * 384 + 256 + ks * 32 + quad * 8;
    *(short8*)&smA[((m * 4 + ks) * 64 + lane) * 8] = *(const short8*)src;
  }
  // ---- stage B from ipw_bf 96KB (24 chunks/wave) ----
#pragma unroll
  for (int s = 0; s < 24; s++) {
    const int i = wv * 24 + s, ct = i >> 2, ks = i & 3;
    const __hip_bfloat16* src = ipw_bf + (size_t)(ct * 16 + lr) * 128 + ks * 32 + quad * 8;
    *(short8*)&smB[((ct * 4 + ks) * 64 + lane) * 8] = *(const short8*)src;
  }
  __syncthreads();
  // ---- MFMA: wave owns cols [wv*96, wv*96+96) x all 8 m-tiles ----
  f32x4 acc[8][6];
#pragma unroll
  for (int m = 0; m < 8; m++)
#pragma unroll
    for (int c = 0; c < 6; c++) acc[m][c] = (f32x4){0.f, 0.f, 0.f, 0.f};
#pragma unroll
  for (int ks = 0; ks < 4; ks++) {
    short8 a[8];
#pragma unroll
    for (int m = 0; m < 8; m++)
      a[m] = *(const short8*)&smA[((m * 4 + ks) * 64 + lane) * 8];
#pragma unroll
    for (int c = 0; c < 6; c++) {
      const int ct = wv * 6 + c;
      short8 b = *(const short8*)&smB[((ct * 4 + ks) * 64 + lane) * 8];
#pragma unroll
      for (int m = 0; m < 8; m++)
        acc[m][c] = __builtin_amdgcn_mfma_f32_16x16x32_bf16(a[m], b, acc[m][c], 0, 0, 0);
    }
  }
  __syncthreads();                       // all waves done with smA/smB
  // ---- epilogue: +ipb, cvt, LDS transpose [128][392], coalesced store ----
  __hip_bfloat16* C = sm2;               // 128*392 = 50176 elems <= 65536
#pragma unroll
  for (int c = 0; c < 6; c++) {
    const int col = wv * 96 + c * 16 + lr;
    const float bv = ipb[col];
#pragma unroll
    for (int m = 0; m < 8; m++)
#pragma unroll
      for (int rr = 0; rr < 4; rr++)
        C[(m * 16 + quad * 4 + rr) * 392 + col] = __float2bfloat16(acc[m][c][rr] + bv);
  }
  __syncthreads();
  {
    const int r = t >> 1, h = t & 1;
    __hip_bfloat16* dst = qkv + (bm0 + r) * 384 + h * 192;
    const __hip_bfloat16* sp = &C[r * 392 + h * 192];
#pragma unroll
    for (int q = 0; q < 24; q++)
      *(short8*)(dst + q * 8) = *(const short8*)(sp + q * 8);
  }
}

// ---------------- K3: collapsed attention -> mean_ctx [B,128] ----------------
__global__ __launch_bounds__(192) void k3_attn(
    const __hip_bfloat16* __restrict__ qkv_sel, const float* __restrict__ ipb,
    float* __restrict__ mean_ctx)
{
  __shared__ float qt[384][17];
  __shared__ float sm[8][17][18];
  __shared__ float cw[8][18];
  const int b = blockIdx.x, t = threadIdx.x;
  const __hip_bfloat16* src = qkv_sel + (size_t)b * 6144;
  // vectorized load: 768 short8 chunks (16 rows x 48 chunks), 4 per thread
  for (int s = t; s < 768; s += 192) {
    int j = s / 48, c8 = s - j * 48;
    short8 v = *(const short8*)(src + j * 384 + c8 * 8);
    const __hip_bfloat16* hp = (const __hip_bfloat16*)&v;
#pragma unroll
    for (int q = 0; q < 8; q++) qt[c8 * 8 + q][j] = __bfloat162float(hp[q]);
  }
  for (int c = t; c < 384; c += 192) qt[c][16] = ipb[c];
  __syncthreads();
  if (t < 136) {
    int h = t / 17, qi = t % 17;
    const int qb = h * 16, kbx = 128 + h * 16;
    float qv[16];
#pragma unroll
    for (int d = 0; d < 16; d++) qv[d] = qt[qb + d][qi];
    for (int ki = 0; ki < 17; ki++) {
      float s = 0.f;
#pragma unroll
      for (int d = 0; d < 16; d++) s += qv[d] * qt[kbx + d][ki];
      sm[h][qi][ki] = s * 0.25f;
    }
  }
  __syncthreads();
  if (t < 136) {
    int h = t / 17, qi = t % 17;
    float m = -__builtin_inff();
    for (int ki = 0; ki < 17; ki++) m = fmaxf(m, sm[h][qi][ki]);
    float e[17], den = 0.f;
#pragma unroll
    for (int ki = 0; ki < 17; ki++) {
      e[ki] = expf(sm[h][qi][ki] - m);
      den += (ki == 16 ? 48.f : 1.f) * e[ki];
    }
    float mult = (qi == 16) ? 48.f : 1.f;
    float inv = mult / den;
#pragma unroll
    for (int ki = 0; ki < 17; ki++) sm[h][qi][ki] = e[ki] * inv;
  }
  __syncthreads();
  if (t < 136) {
    int h = t / 17, ki = t % 17;
    float s = 0.f;
    for (int qi = 0; qi < 17; qi++) s += sm[h][qi][ki];
    cw[h][ki] = s * ((ki == 16) ? 48.f : 1.f) * (1.f / 64.f);
  }
  __syncthreads();
  if (t < 128) {
    int h = t >> 4, d = t & 15;
    int vb = 256 + h * 16 + d;
    float s = 0.f;
#pragma unroll
    for (int ki = 0; ki < 17; ki++) s += cw[h][ki] * qt[vb][ki];
    mean_ctx[(size_t)b * 128 + t] = s;
  }
}

// ---------------- K4: enhanced_x = x + mean_ctx @ M^T + b' ----------------
__global__ __launch_bounds__(256) void k4_out(
    const float* __restrict__ x, const float* __restrict__ mc,
    const float* __restrict__ M, const float* __restrict__ bf,
    float* __restrict__ out)
{
  __shared__ float ms[32][128];
  __shared__ float wt[128][65];
  const int t = threadIdx.x;
  const int b0 = blockIdx.x * 32;
  {
    int r = t >> 3, c0 = (t & 7) * 16;
    const float* s = mc + (size_t)(b0 + r) * 128 + c0;
#pragma unroll
    for (int q = 0; q < 16; q++) ms[r][c0 + q] = s[q];
  }
  const int i = t & 127, rg = t >> 7;
  const int il = t >> 1, kb = (t & 1) * 32;
  for (int oc = 0; oc < 4; oc++) {
    float acc[16];
#pragma unroll
    for (int rr = 0; rr < 16; rr++) acc[rr] = 0.f;
    for (int kc = 0; kc < 128; kc += 64) {
      __syncthreads();
      const float* wr = M + (oc * 128 + il) * 128 + kc + kb;
#pragma unroll
      for (int q = 0; q < 32; q++) wt[il][kb + q] = wr[q];
      __syncthreads();
#pragma unroll
      for (int kk = 0; kk < 64; kk++) {
        float w = wt[i][kk];
#pragma unroll
        for (int rr = 0; rr < 16; rr++) acc[rr] += w * ms[rg * 16 + rr][kc + kk];
      }
    }
    float bb = bf[oc * 128 + i];
#pragma unroll
    for (int rr = 0; rr < 16; rr++) {
      size_t idx = (size_t)(b0 + rg * 16 + rr) * 512 + oc * 128 + i;
      out[idx] = x[idx] + acc[rr] + bb;
    }
  }
}

// ---------------- host ----------------
extern "C" void kernel_launch(void* const* d_in, const int* in_sizes, int n_in,
                              void* d_out, int out_size, void* d_ws, size_t ws_size,
                              hipStream_t stream)
{
  const float* x      = (const float*)d_in[0];
  const float* af     = (const float*)d_in[1];
  const float* costs  = (const float*)d_in[2];
  const float* ue_w1  = (const float*)d_in[3];
  const float* ue_b1  = (const float*)d_in[4];
  const float* ue_w2  = (const float*)d_in[5];
  const float* ue_b2  = (const float*)d_in[6];
  const float* fi_w1  = (const float*)d_in[7];
  const float* fi_b1  = (const float*)d_in[8];
  const float* fi_w2  = (const float*)d_in[9];
  const float* fi_b2  = (const float*)d_in[10];
  const float* sd_w1  = (const float*)d_in[11];
  const float* sd_b1  = (const float*)d_in[12];
  const float* sd_w2  = (const float*)d_in[13];
  const float* sd_b2  = (const float*)d_in[14];
  const float* enc_w  = (const float*)d_in[15];
  const float* enc_b  = (const float*)d_in[16];
  const float* ipw    = (const float*)d_in[17];
  const float* ipb    = (const float*)d_in[18];
  const float* opjw   = (const float*)d_in[19];
  const float* opjb   = (const float*)d_in[20];
  const float* op_w   = (const float*)d_in[21];
  const float* op_b   = (const float*)d_in[22];

  float* out = (float*)d_out;
  float* out_enh  = out;                    // [B,512]
  float* out_unc  = out + 4194304;          // [B,1]
  float* out_fi   = out_unc + 8192;         // [B,64]
  float* out_sp   = out_fi + 524288;        // [B,64]
  float* out_mask = out_sp + 524288;        // [B,64]
  float* out_cost = out_mask + 524288;      // [B]

  char* ws = (char*)d_ws;
  __hip_bfloat16* qkv     = (__hip_bfloat16*)ws;                  // 100,663,296 B
  // G1-G4 scratch aliased into low qkv region (dead before K2a/K2b touch qkv):
  float*          H1      = (float*)ws;                           // 8 MB [8192,256]
  float*          H2      = (float*)(ws + 8388608);               // 4 MB [8192,128]
  float*          FIws    = (float*)(ws + 12582912);              // 2 MB [8192,64]
  __hip_bfloat16* encw_bf = (__hip_bfloat16*)(ws + 100663296);    // 4,194,304 B (K0b->K2a)
  float*          mc      = (float*)(ws + 100663296);             // alias: K3->K4 (4 MB)
  __hip_bfloat16* ipw_bf  = (__hip_bfloat16*)(ws + 104857600);    // 98,304 B
  float*          M       = (float*)(ws + 104955904);             // 262,144 B
  float*          bfv     = (float*)(ws + 105218048);             // 2,048 B
  int*            rows    = (int*)(ws + 105220096);               // 2,097,152 B
  int*            counts  = (int*)(ws + 107317248);               // 256 B

  hipMemsetAsync(counts, 0, 64 * sizeof(int), stream);
  k0_fuse<<<257, 256, 0, stream>>>(op_w, opjw, opjb, op_b, M, bfv);
  k0b_cvt<<<2096, 256, 0, stream>>>(enc_w, ipw, encw_bf, ipw_bf);
  g1_h1<<<dim3(128, 4), 256, 0, stream>>>(x, ue_w1, ue_b1, fi_w1, fi_b1, H1);
  g2_fi<<<512, 256, 0, stream>>>(H1, ue_w2, ue_b2, fi_w2, fi_b2,
                                 out_unc, out_fi, FIws);
  g3_h2<<<dim3(256, 2), 256, 0, stream>>>(x, FIws, sd_w1, sd_b1, H2);
  g4_sel<<<512, 256, 0, stream>>>(H2, costs, sd_w2, sd_b2, out_unc,
                                  out_sp, out_mask, out_cost, rows, counts);
  k2a_enc<<<dim3(64, 64), 256, 0, stream>>>(af, encw_bf, enc_b, rows, counts, qkv);
  k2b_qkv<<<1024, 256, 0, stream>>>(ipw_bf, ipb, qkv);
  k3_attn<<<8192, 192, 0, stream>>>(qkv, ipb, mc);
  k4_out<<<256, 256, 0, stream>>>(x, mc, M, bfv, out_enh);
}